// Round 7
// baseline (8430.548 us; speedup 1.0000x reference)
//
#include <hip/hip_runtime.h>
#include <hip/hip_bf16.h>

#define TT 3650
#define HH 256

typedef _Float16 f16x2 __attribute__((ext_vector_type(2)));
typedef _Float16 f16x8 __attribute__((ext_vector_type(8)));
struct H4q { f16x2 a, b, c, d; };

__device__ __forceinline__ float xexp2(float x) { return __builtin_amdgcn_exp2f(x); }
__device__ __forceinline__ float xrcp(float x) { return __builtin_amdgcn_rcpf(x); }
__device__ __forceinline__ float xexp(float x) { return xexp2(x * 1.4426950408889634f); }
__device__ __forceinline__ float xtanh(float x) {
  float e = xexp2(x * 2.8853900817779268f);  // e^{2x}
  return 1.0f - 2.0f * xrcp(e + 1.0f);
}
// _step_function(x) = (tanh(5x)+1)/2 == sigmoid(10x)
__device__ __forceinline__ float xstep(float x) {
  return xrcp(1.0f + xexp2(-14.426950408889634f * x));
}
__device__ __forceinline__ float xsinh(float x) {
  float e = xexp(x);
  return 0.5f * (e - xrcp(e));
}

#if __has_builtin(__builtin_amdgcn_fdot2)
__device__ __forceinline__ float xdot2(f16x2 a, f16x2 b, float c) {
  return __builtin_amdgcn_fdot2(a, b, c, false);
}
#else
__device__ __forceinline__ float xdot2(f16x2 a, f16x2 b, float c) {
  return c + (float)a[0] * (float)b[0] + (float)a[1] * (float)b[1];
}
#endif

#define REP32(M) M(0) M(1) M(2) M(3) M(4) M(5) M(6) M(7) M(8) M(9) M(10) M(11) \
  M(12) M(13) M(14) M(15) M(16) M(17) M(18) M(19) M(20) M(21) M(22) M(23) \
  M(24) M(25) M(26) M(27) M(28) M(29) M(30) M(31)

// LDS pad: total ~86 KB -> compiler must assume ONE 1024-thread block/CU
// (16 waves = 4 waves/EU) -> VGPR budget 128/wave. Our pinned live set (~100)
// fits that budget, so the register pins below cannot cause spills.
#define LDS_PAD 10240

// activation buffer: 4 quads of 64 f16 (128 B) + 16 B pad each (stride 144 B)
// so the 4 distinct per-wave ds_read_b128 broadcast addresses (one per q) hit
// disjoint bank groups (unpadded 128 B stride == bank period -> 4-way conflict)
#define QSTRIDE_E 72  // f16 elements per quad incl pad

__global__ void __launch_bounds__(1024)
    __attribute__((amdgpu_waves_per_eu(4, 4))) exphydro_scan(
    const float* __restrict__ gin, const float* __restrict__ gdayl,
    const float* __restrict__ gW0, const float* __restrict__ gb0,
    const float* __restrict__ gW1, const float* __restrict__ gb1,
    const float* __restrict__ gW2, const float* __restrict__ gb2,
    const float* __restrict__ gWout, const float* __restrict__ gbout,
    float* __restrict__ gout) {
  __shared__ alignas(16) _Float16 h0h[4 * QSTRIDE_E];
  __shared__ alignas(16) _Float16 h1h[4 * QSTRIDE_E];
  __shared__ float sWP[80];                  // [m][wave]: m*16+w, m=0..4, w=0..15
  __shared__ float sP[TT], sTm[TT];
  __shared__ float sLd[TT + LDS_PAD];        // + occupancy-assumption pad

  const int tid = threadIdx.x;
  const int j = tid >> 2;      // output neuron 0..255
  const int q = tid & 3;       // k-quad: k in [64q, 64q+64)
  const int lane = tid & 63;
  const int wave = tid >> 6;   // 0..15

  // ---- stage forcings to LDS ----
  for (int i = tid; i < TT; i += 1024) {
    sP[i] = gin[5 * i + 2];
    sTm[i] = gin[5 * i + 3];
    sLd[i] = gdayl[i];
  }

  // ---- per-thread constants in registers ----
  float s0 = gin[0], s1 = gin[1];
  const float bo0 = gbout[0], bo1 = gbout[1], bo2 = gbout[2], bo3 = gbout[3],
              bo4 = gbout[4];
  const float w00 = gW0[j], w01 = gW0[HH + j], w02 = gW0[2 * HH + j],
              w03 = gW0[3 * HH + j];
  const float b0 = gb0[j], b1 = gb1[j], b2 = gb2[j];
  const float wo_a = gWout[5 * j + q];       // m = q (0..3)
  const float wo_c = gWout[5 * j + 4];       // m = 4 (used by q==0)

  // ---- big weights into 64 NAMED registers/thread as packed fp16 ----
  // thread (j,q) holds W1[k][j], W2[k][j] for k in [64q, 64q+64)
  const int kbase = q * 64;
#define WDECL(i) f16x2 w1_##i, w2_##i;
  REP32(WDECL)
#undef WDECL
#define WINIT(i)                                                            \
  {                                                                         \
    const float* p1 = gW1 + (kbase + 2 * (i)) * HH + j;                     \
    const float* p2 = gW2 + (kbase + 2 * (i)) * HH + j;                     \
    w1_##i = f16x2{(_Float16)p1[0], (_Float16)p1[HH]};                      \
    w2_##i = f16x2{(_Float16)p2[0], (_Float16)p2[HH]};                      \
  }
  REP32(WINIT)
#undef WINIT

  const char* hb0 = (const char*)h0h + q * 144;  // this thread's 64-k window
  const char* hb1 = (const char*)h1h + q * 144;
  const int jw = (j >> 6) * QSTRIDE_E + (j & 63); // writer slot for neuron j

  __syncthreads();  // staging visible

  for (int t = 0; t < TT; ++t) {
    // ---- REGISTER PIN: empty asm "redefines" every weight register each
    // iteration, making them loop-carried values the compiler CANNOT
    // rematerialize or sink back into the loop as loads (rounds 3-6 showed
    // the backend re-loading them every step; VGPR_Count 60 < 64 proved it).
#define WPIN(i) asm volatile("" : "+v"(w1_##i), "+v"(w2_##i));
    REP32(WPIN)
#undef WPIN

    const float p_in = sP[t];
    const float tm = sTm[t];
    const float ld = sLd[t];

    // ---- layer 0 (4x redundant across q) ----
    float z0 = b0 + s0 * w00 + s1 * w01 + p_in * w02 + tm * w03;
    float h0v = xtanh(z0);
    if (q == 0) h0h[jw] = (_Float16)h0v;
    __syncthreads();  // A

    // ---- layer 1: 32 fdot2 over this thread's k-quad ----
    float a0 = 0.f, a1 = 0.f, a2 = 0.f, a3 = 0.f;
#define LSTEP(s, hb, wA, wB, wC, wD)                                        \
  {                                                                         \
    f16x8 hv = *(const f16x8*)((hb) + (s) * 16);                            \
    H4q hp = __builtin_bit_cast(H4q, hv);                                   \
    a0 = xdot2(hp.a, wA, a0);                                               \
    a1 = xdot2(hp.b, wB, a1);                                               \
    a2 = xdot2(hp.c, wC, a2);                                               \
    a3 = xdot2(hp.d, wD, a3);                                               \
  }
    LSTEP(0, hb0, w1_0, w1_1, w1_2, w1_3)
    LSTEP(1, hb0, w1_4, w1_5, w1_6, w1_7)
    LSTEP(2, hb0, w1_8, w1_9, w1_10, w1_11)
    LSTEP(3, hb0, w1_12, w1_13, w1_14, w1_15)
    LSTEP(4, hb0, w1_16, w1_17, w1_18, w1_19)
    LSTEP(5, hb0, w1_20, w1_21, w1_22, w1_23)
    LSTEP(6, hb0, w1_24, w1_25, w1_26, w1_27)
    LSTEP(7, hb0, w1_28, w1_29, w1_30, w1_31)
    float z1 = (a0 + a1) + (a2 + a3);
    z1 += __shfl_xor(z1, 1);   // combine 4 k-quads
    z1 += __shfl_xor(z1, 2);
    float h1v = xtanh(z1 + b1);
    if (q == 0) h1h[jw] = (_Float16)h1v;
    __syncthreads();  // B

    // ---- layer 2 ----
    a0 = 0.f; a1 = 0.f; a2 = 0.f; a3 = 0.f;
    LSTEP(0, hb1, w2_0, w2_1, w2_2, w2_3)
    LSTEP(1, hb1, w2_4, w2_5, w2_6, w2_7)
    LSTEP(2, hb1, w2_8, w2_9, w2_10, w2_11)
    LSTEP(3, hb1, w2_12, w2_13, w2_14, w2_15)
    LSTEP(4, hb1, w2_16, w2_17, w2_18, w2_19)
    LSTEP(5, hb1, w2_20, w2_21, w2_22, w2_23)
    LSTEP(6, hb1, w2_24, w2_25, w2_26, w2_27)
    LSTEP(7, hb1, w2_28, w2_29, w2_30, w2_31)
#undef LSTEP
    float z2 = (a0 + a1) + (a2 + a3);
    z2 += __shfl_xor(z2, 1);
    z2 += __shfl_xor(z2, 2);
    float h2v = xtanh(z2 + b2);

    // ---- output partials: q carries m=q; q==0 also m=4 ----
    float pa = h2v * wo_a;
    float pc = (q == 0) ? h2v * wo_c : 0.0f;
#pragma unroll
    for (int off = 4; off < 64; off <<= 1) {  // reduce over the wave's 16 j's
      pa += __shfl_xor(pa, off);
      pc += __shfl_xor(pc, off);
    }
    if (lane < 4) sWP[lane * 16 + wave] = pa;  // lane==q for j-group 0
    if (lane == 0) sWP[64 + wave] = pc;
    __syncthreads();  // C

    // ---- finalize on ALL threads (bit-identical), state in registers ----
    float ov = sWP[lane];            // lane = m*16 + w for m=0..3
    float ov4 = sWP[64 + (lane & 15)];
    ov += __shfl_xor(ov, 1);
    ov4 += __shfl_xor(ov4, 1);
    ov += __shfl_xor(ov, 2);
    ov4 += __shfl_xor(ov4, 2);
    ov += __shfl_xor(ov, 4);
    ov4 += __shfl_xor(ov4, 4);
    ov += __shfl_xor(ov, 8);
    ov4 += __shfl_xor(ov4, 8);
    float o0 = __shfl(ov, 0) + bo0;
    float o1 = __shfl(ov, 16) + bo1;
    float o2 = __shfl(ov, 32) + bo2;
    float o3 = __shfl(ov, 48) + bo3;
    float o4 = ov4 + bo4;
    if (tid == 0) {
      gout[t] = o4;           // q_output[t] = raw mlp output m=4 at state_t
      gout[TT + t] = s0;      // s_snow_nn[t] (pre-update)
      gout[2 * TT + t] = s1;  // s_water_nn[t]
    }
    float sh0 = xsinh(o0), sh1 = xsinh(o1), sh2 = xsinh(o2);
    float e3 = xexp(o3), e4 = xexp(o4);
    float stn = xstep(-tm), st0 = xstep(s0), st1 = xstep(s1);
    float psn = fmaxf(sh0 * stn, 0.0f);
    float prn = fmaxf(sh1, 0.0f);
    float mm = fmaxf(st0 * sh2, 0.0f);
    float evt = st1 * e3 * ld;
    float qq = st1 * e4;
    s0 += psn - mm;                 // DT = 1
    s1 += prn + mm - evt - qq;
  }
}

extern "C" void kernel_launch(void* const* d_in, const int* in_sizes, int n_in,
                              void* d_out, int out_size, void* d_ws, size_t ws_size,
                              hipStream_t stream) {
  const float* gin   = (const float*)d_in[0];
  const float* gdayl = (const float*)d_in[1];
  const float* gW0   = (const float*)d_in[2];
  const float* gb0   = (const float*)d_in[3];
  const float* gW1   = (const float*)d_in[4];
  const float* gb1   = (const float*)d_in[5];
  const float* gW2   = (const float*)d_in[6];
  const float* gb2   = (const float*)d_in[7];
  const float* gWout = (const float*)d_in[8];
  const float* gbout = (const float*)d_in[9];
  float* gout = (float*)d_out;
  exphydro_scan<<<dim3(1), dim3(1024), 0, stream>>>(
      gin, gdayl, gW0, gb0, gW1, gb1, gW2, gb2, gWout, gbout, gout);
}

// Round 8
// 8415.907 us; speedup vs baseline: 1.0017x; 1.0017x over previous
//
#include <hip/hip_runtime.h>
#include <hip/hip_bf16.h>

#define TT 3650
#define HH 256

typedef _Float16 f16x2 __attribute__((ext_vector_type(2)));
typedef _Float16 f16x8 __attribute__((ext_vector_type(8)));
struct H4q { f16x2 a, b, c, d; };

__device__ __forceinline__ float xexp2(float x) { return __builtin_amdgcn_exp2f(x); }
__device__ __forceinline__ float xrcp(float x) { return __builtin_amdgcn_rcpf(x); }
__device__ __forceinline__ float xexp(float x) { return xexp2(x * 1.4426950408889634f); }
__device__ __forceinline__ float xtanh(float x) {
  float e = xexp2(x * 2.8853900817779268f);  // e^{2x}
  return 1.0f - 2.0f * xrcp(e + 1.0f);
}
// _step_function(x) = (tanh(5x)+1)/2 == sigmoid(10x)
__device__ __forceinline__ float xstep(float x) {
  return xrcp(1.0f + xexp2(-14.426950408889634f * x));
}
__device__ __forceinline__ float xsinh(float x) {
  float e = xexp(x);
  return 0.5f * (e - xrcp(e));
}

#if __has_builtin(__builtin_amdgcn_fdot2)
__device__ __forceinline__ float xdot2(f16x2 a, f16x2 b, float c) {
  return __builtin_amdgcn_fdot2(a, b, c, false);
}
#else
__device__ __forceinline__ float xdot2(f16x2 a, f16x2 b, float c) {
  return c + (float)a[0] * (float)b[0] + (float)a[1] * (float)b[1];
}
#endif

#define REP64(M) M(0) M(1) M(2) M(3) M(4) M(5) M(6) M(7) M(8) M(9) M(10) M(11) \
  M(12) M(13) M(14) M(15) M(16) M(17) M(18) M(19) M(20) M(21) M(22) M(23) \
  M(24) M(25) M(26) M(27) M(28) M(29) M(30) M(31) M(32) M(33) M(34) M(35) \
  M(36) M(37) M(38) M(39) M(40) M(41) M(42) M(43) M(44) M(45) M(46) M(47) \
  M(48) M(49) M(50) M(51) M(52) M(53) M(54) M(55) M(56) M(57) M(58) M(59) \
  M(60) M(61) M(62) M(63)

// LDS pad: keep total ~86 KB so at most ONE block/CU is resident (we launch
// one 8-wave block; no reason to let the compiler assume more co-residency).
#define LDS_PAD 10240

__global__ void __launch_bounds__(512) exphydro_scan(
    const float* __restrict__ gin, const float* __restrict__ gdayl,
    const float* __restrict__ gW0, const float* __restrict__ gb0,
    const float* __restrict__ gW1, const float* __restrict__ gb1,
    const float* __restrict__ gW2, const float* __restrict__ gb2,
    const float* __restrict__ gWout, const float* __restrict__ gbout,
    float* __restrict__ gout) {
  // activations: halves separated by 16B pad so the two per-wave broadcast
  // addresses of each ds_read_b128 land on disjoint bank groups
  __shared__ alignas(16) _Float16 h0h[HH + 8];
  __shared__ alignas(16) _Float16 h1h[HH + 8];
  __shared__ float sWP[64];                  // [m][wave] partials, m*8+w, 40 used
  __shared__ float sP[TT], sTm[TT];
  __shared__ float sLd[TT + LDS_PAD];        // + occupancy-assumption pad

  const int tid = threadIdx.x;
  const int j = tid >> 1;      // output neuron 0..255
  const int q = tid & 1;       // k-half 0..1 (k in [128q, 128q+128))
  const int lane = tid & 63;

  // ---- stage forcings to LDS ----
  for (int i = tid; i < TT; i += 512) {
    sP[i] = gin[5 * i + 2];
    sTm[i] = gin[5 * i + 3];
    sLd[i] = gdayl[i];
  }

  // ---- per-thread constants in registers ----
  float s0 = gin[0], s1 = gin[1];
  const float bo0 = gbout[0], bo1 = gbout[1], bo2 = gbout[2], bo3 = gbout[3],
              bo4 = gbout[4];
  const float w00 = gW0[j], w01 = gW0[HH + j], w02 = gW0[2 * HH + j],
              w03 = gW0[3 * HH + j];
  const float b0 = gb0[j], b1 = gb1[j], b2 = gb2[j];
  const float wo_a = gWout[5 * j + q];       // m = q
  const float wo_b = gWout[5 * j + 2 + q];   // m = 2+q
  const float wo_c = gWout[5 * j + 4];       // m = 4 (used by q==0)

  // ---- big weights into 128 AGPRs/thread (accumulator file — idle here).
  // The v-class allocator has refused to keep these resident for 5 rounds
  // (budget heuristic ~64 VGPRs); the a-class file is a separate 128-KB/CU
  // resource the scalar pipeline never touches. Volatile writes pin the init
  // in the preheader; volatile reads in-loop prevent LICM re-hoisting.
  const int kbase = q * 128;
#define WDECL(i) unsigned wa1_##i, wa2_##i;
  REP64(WDECL)
#undef WDECL
#define WINIT(i)                                                            \
  {                                                                         \
    const float* p1 = gW1 + (kbase + 2 * (i)) * HH + j;                     \
    const float* p2 = gW2 + (kbase + 2 * (i)) * HH + j;                     \
    f16x2 t1 = f16x2{(_Float16)p1[0], (_Float16)p1[HH]};                    \
    f16x2 t2 = f16x2{(_Float16)p2[0], (_Float16)p2[HH]};                    \
    asm volatile("v_accvgpr_write_b32 %0, %1"                               \
                 : "=a"(wa1_##i) : "v"(__builtin_bit_cast(unsigned, t1)));  \
    asm volatile("v_accvgpr_write_b32 %0, %1"                               \
                 : "=a"(wa2_##i) : "v"(__builtin_bit_cast(unsigned, t2)));  \
  }
  REP64(WINIT)
#undef WINIT

  const char* hb0 = (const char*)h0h + q * 272;  // this thread's 128-half window
  const char* hb1 = (const char*)h1h + q * 272;
  const int jw = j + ((j & 128) >> 4);           // +8 elements for upper half

  __syncthreads();  // staging visible

  for (int t = 0; t < TT; ++t) {
    const float p_in = sP[t];
    const float tm = sTm[t];
    const float ld = sLd[t];

    // ---- layer 0 (2x redundant across q) ----
    float z0 = b0 + s0 * w00 + s1 * w01 + p_in * w02 + tm * w03;
    float h0v = xtanh(z0);
    if (q == 0) h0h[jw] = (_Float16)h0v;
    __syncthreads();  // A

    // ---- layer 1: 64 fdot2; weights pulled from AGPR right before use ----
    float a0 = 0.f, a1 = 0.f, a2 = 0.f, a3 = 0.f;
#define AREAD(dst, src)                                                     \
  asm volatile("v_accvgpr_read_b32 %0, %1" : "=v"(dst) : "a"(src));
#define LSTEP1(s, i0, i1, i2, i3)                                           \
  {                                                                         \
    f16x8 hv = *(const f16x8*)(hb0 + (s) * 16);                             \
    H4q hp = __builtin_bit_cast(H4q, hv);                                   \
    unsigned u0, u1, u2, u3;                                                \
    AREAD(u0, wa1_##i0) AREAD(u1, wa1_##i1)                                 \
    AREAD(u2, wa1_##i2) AREAD(u3, wa1_##i3)                                 \
    a0 = xdot2(hp.a, __builtin_bit_cast(f16x2, u0), a0);                    \
    a1 = xdot2(hp.b, __builtin_bit_cast(f16x2, u1), a1);                    \
    a2 = xdot2(hp.c, __builtin_bit_cast(f16x2, u2), a2);                    \
    a3 = xdot2(hp.d, __builtin_bit_cast(f16x2, u3), a3);                    \
  }
#define LSTEP2(s, i0, i1, i2, i3)                                           \
  {                                                                         \
    f16x8 hv = *(const f16x8*)(hb1 + (s) * 16);                             \
    H4q hp = __builtin_bit_cast(H4q, hv);                                   \
    unsigned u0, u1, u2, u3;                                                \
    AREAD(u0, wa2_##i0) AREAD(u1, wa2_##i1)                                 \
    AREAD(u2, wa2_##i2) AREAD(u3, wa2_##i3)                                 \
    a0 = xdot2(hp.a, __builtin_bit_cast(f16x2, u0), a0);                    \
    a1 = xdot2(hp.b, __builtin_bit_cast(f16x2, u1), a1);                    \
    a2 = xdot2(hp.c, __builtin_bit_cast(f16x2, u2), a2);                    \
    a3 = xdot2(hp.d, __builtin_bit_cast(f16x2, u3), a3);                    \
  }
    LSTEP1(0, 0, 1, 2, 3)
    LSTEP1(1, 4, 5, 6, 7)
    LSTEP1(2, 8, 9, 10, 11)
    LSTEP1(3, 12, 13, 14, 15)
    LSTEP1(4, 16, 17, 18, 19)
    LSTEP1(5, 20, 21, 22, 23)
    LSTEP1(6, 24, 25, 26, 27)
    LSTEP1(7, 28, 29, 30, 31)
    LSTEP1(8, 32, 33, 34, 35)
    LSTEP1(9, 36, 37, 38, 39)
    LSTEP1(10, 40, 41, 42, 43)
    LSTEP1(11, 44, 45, 46, 47)
    LSTEP1(12, 48, 49, 50, 51)
    LSTEP1(13, 52, 53, 54, 55)
    LSTEP1(14, 56, 57, 58, 59)
    LSTEP1(15, 60, 61, 62, 63)
    float z1 = (a0 + a1) + (a2 + a3);
    z1 += __shfl_xor(z1, 1);  // combine the two k-halves
    float h1v = xtanh(z1 + b1);
    if (q == 0) h1h[jw] = (_Float16)h1v;
    __syncthreads();  // B

    // ---- layer 2 ----
    a0 = 0.f; a1 = 0.f; a2 = 0.f; a3 = 0.f;
    LSTEP2(0, 0, 1, 2, 3)
    LSTEP2(1, 4, 5, 6, 7)
    LSTEP2(2, 8, 9, 10, 11)
    LSTEP2(3, 12, 13, 14, 15)
    LSTEP2(4, 16, 17, 18, 19)
    LSTEP2(5, 20, 21, 22, 23)
    LSTEP2(6, 24, 25, 26, 27)
    LSTEP2(7, 28, 29, 30, 31)
    LSTEP2(8, 32, 33, 34, 35)
    LSTEP2(9, 36, 37, 38, 39)
    LSTEP2(10, 40, 41, 42, 43)
    LSTEP2(11, 44, 45, 46, 47)
    LSTEP2(12, 48, 49, 50, 51)
    LSTEP2(13, 52, 53, 54, 55)
    LSTEP2(14, 56, 57, 58, 59)
    LSTEP2(15, 60, 61, 62, 63)
#undef LSTEP1
#undef LSTEP2
#undef AREAD
    float z2 = (a0 + a1) + (a2 + a3);
    z2 += __shfl_xor(z2, 1);
    float h2v = xtanh(z2 + b2);

    // ---- output partials: in-wave reduce over j (q-parity carries m pairs) ----
    float pa = h2v * wo_a;                    // m = q
    float pb = h2v * wo_b;                    // m = 2+q
    float pc = (q == 0) ? h2v * wo_c : 0.0f;  // m = 4
#pragma unroll
    for (int off = 2; off < 64; off <<= 1) {
      pa += __shfl_xor(pa, off);
      pb += __shfl_xor(pb, off);
      pc += __shfl_xor(pc, off);
    }
    {
      const int wave = tid >> 6;
      if (lane == 0) {
        sWP[0 + wave] = pa; sWP[16 + wave] = pb; sWP[32 + wave] = pc;
      } else if (lane == 1) {
        sWP[8 + wave] = pa; sWP[24 + wave] = pb;
      }
    }
    __syncthreads();  // C

    // ---- finalize on ALL threads (bit-identical), state stays in registers ----
    float ov = (lane < 40) ? sWP[lane] : 0.0f;  // lane = m*8 + w
    ov += __shfl_xor(ov, 1);
    ov += __shfl_xor(ov, 2);
    ov += __shfl_xor(ov, 4);
    float o0 = __shfl(ov, 0) + bo0;
    float o1 = __shfl(ov, 8) + bo1;
    float o2 = __shfl(ov, 16) + bo2;
    float o3 = __shfl(ov, 24) + bo3;
    float o4 = __shfl(ov, 32) + bo4;
    if (tid == 0) {
      gout[t] = o4;           // q_output[t] = raw mlp output m=4 at state_t
      gout[TT + t] = s0;      // s_snow_nn[t] (pre-update)
      gout[2 * TT + t] = s1;  // s_water_nn[t]
    }
    float sh0 = xsinh(o0), sh1 = xsinh(o1), sh2 = xsinh(o2);
    float e3 = xexp(o3), e4 = xexp(o4);
    float stn = xstep(-tm), st0 = xstep(s0), st1 = xstep(s1);
    float psn = fmaxf(sh0 * stn, 0.0f);
    float prn = fmaxf(sh1, 0.0f);
    float mm = fmaxf(st0 * sh2, 0.0f);
    float evt = st1 * e3 * ld;
    float qq = st1 * e4;
    s0 += psn - mm;                 // DT = 1
    s1 += prn + mm - evt - qq;
  }
}

extern "C" void kernel_launch(void* const* d_in, const int* in_sizes, int n_in,
                              void* d_out, int out_size, void* d_ws, size_t ws_size,
                              hipStream_t stream) {
  const float* gin   = (const float*)d_in[0];
  const float* gdayl = (const float*)d_in[1];
  const float* gW0   = (const float*)d_in[2];
  const float* gb0   = (const float*)d_in[3];
  const float* gW1   = (const float*)d_in[4];
  const float* gb1   = (const float*)d_in[5];
  const float* gW2   = (const float*)d_in[6];
  const float* gb2   = (const float*)d_in[7];
  const float* gWout = (const float*)d_in[8];
  const float* gbout = (const float*)d_in[9];
  float* gout = (float*)d_out;
  exphydro_scan<<<dim3(1), dim3(512), 0, stream>>>(
      gin, gdayl, gW0, gb0, gW1, gb1, gW2, gb2, gWout, gbout, gout);
}

// Round 10
// 5235.253 us; speedup vs baseline: 1.6103x; 1.6075x over previous
//
#include <hip/hip_runtime.h>
#include <hip/hip_bf16.h>

#define TT 3650
#define HH 256
#define LDS_PAD 10240

typedef _Float16 f16x8 __attribute__((ext_vector_type(8)));
typedef float f32x4 __attribute__((ext_vector_type(4)));

__device__ __forceinline__ float xexp2(float x) { return __builtin_amdgcn_exp2f(x); }
__device__ __forceinline__ float xrcp(float x) { return __builtin_amdgcn_rcpf(x); }
__device__ __forceinline__ float xexp(float x) { return xexp2(x * 1.4426950408889634f); }
__device__ __forceinline__ float xtanh(float x) {
  float e = xexp2(x * 2.8853900817779268f);  // e^{2x}
  return 1.0f - 2.0f * xrcp(e + 1.0f);
}
__device__ __forceinline__ float xstep(float x) {  // sigmoid(10x)
  return xrcp(1.0f + xexp2(-14.426950408889634f * x));
}
__device__ __forceinline__ float xsinh(float x) {
  float e = xexp(x);
  return 0.5f * (e - xrcp(e));
}

// lane gets its value + the row_ror:N-permuted value (row = 16 lanes)
#define DPPADD(x, ctrl)                                                        \
  (x) += __builtin_bit_cast(float, __builtin_amdgcn_update_dpp(                \
            0, __builtin_bit_cast(int, (x)), (ctrl), 0xf, 0xf, false));

#define REP8(M) M(0) M(1) M(2) M(3) M(4) M(5) M(6) M(7)

// Weights are stored as fp16 of (W * 2^10): removes fp16-denormal weights
// (sigma=0.00625 -> ~0.8% denormal) which the MFMA pipe flushes to zero —
// that systematic z-bias was the 0.055 drift in round 9. Descale after MFMA.
#define WSCALE 1024.0f
#define WDESCALE 0.0009765625f

__global__ void __launch_bounds__(512) exphydro_scan(
    const float* __restrict__ gin, const float* __restrict__ gdayl,
    const float* __restrict__ gW0, const float* __restrict__ gb0,
    const float* __restrict__ gW1, const float* __restrict__ gb1,
    const float* __restrict__ gW2, const float* __restrict__ gb2,
    const float* __restrict__ gWout, const float* __restrict__ gbout,
    float* __restrict__ gout) {
  __shared__ alignas(16) _Float16 h0l[HH];   // 512 B activation buffers
  __shared__ alignas(16) _Float16 h1l[HH];
  __shared__ float sWP[64];                  // [wave][slot]: w*8+m, m=0..4 used
  __shared__ float sP[TT], sTm[TT];
  __shared__ float sLd[TT + LDS_PAD];        // pad keeps 1 block/CU assumption

  const int tid = threadIdx.x;
  const int lane = tid & 63;
  const int w = tid >> 6;          // wave 0..7
  const int li = lane & 15;        // MFMA col within tile
  const int g = lane >> 4;         // k-group 0..3
  const int jA = 32 * w + li;      // this wave's j-tile A
  const int jB = jA + 16;          // j-tile B

  // ---- stage forcings ----
  for (int i = tid; i < TT; i += 512) {
    sP[i] = gin[5 * i + 2];
    sTm[i] = gin[5 * i + 3];
    sLd[i] = gdayl[i];
  }
  if (tid < 64) sWP[tid] = 0.0f;   // slots m=5..7 stay 0 forever

  // ---- per-thread constants ----
  float s0 = gin[0], s1 = gin[1];
  const float bo0 = gbout[0], bo1 = gbout[1], bo2 = gbout[2], bo3 = gbout[3],
              bo4 = gbout[4];
  const float w0A0 = gW0[jA], w0A1 = gW0[HH + jA], w0A2 = gW0[2 * HH + jA],
              w0A3 = gW0[3 * HH + jA];
  const float w0B0 = gW0[jB], w0B1 = gW0[HH + jB], w0B2 = gW0[2 * HH + jB],
              w0B3 = gW0[3 * HH + jB];
  const float b0A = gb0[jA], b0B = gb0[jB], b1A = gb1[jA], b1B = gb1[jB],
              b2A = gb2[jA], b2B = gb2[jB];
  const float woA0 = gWout[5 * jA + 0], woA1 = gWout[5 * jA + 1],
              woA2 = gWout[5 * jA + 2], woA3 = gWout[5 * jA + 3],
              woA4 = gWout[5 * jA + 4];
  const float woB0 = gWout[5 * jB + 0], woB1 = gWout[5 * jB + 1],
              woB2 = gWout[5 * jB + 2], woB3 = gWout[5 * jB + 3],
              woB4 = gWout[5 * jB + 4];

  // ---- weight B-fragments -> AGPRs (native MFMA operands).
  // Fragment for MFMA slice i: lane holds B[k][j=li] for k = 32i + 8g + e.
#define FDECL(i) f16x8 a1A_##i, a1B_##i, a2A_##i, a2B_##i;
  REP8(FDECL)
#undef FDECL
#define MK(dst, G, i, j)                                                       \
  {                                                                            \
    const float* p = (G) + (32 * (i) + g * 8) * HH + (j);                      \
    f16x8 f;                                                                   \
    f[0] = (_Float16)(p[0] * WSCALE);      f[1] = (_Float16)(p[HH] * WSCALE);  \
    f[2] = (_Float16)(p[2 * HH] * WSCALE); f[3] = (_Float16)(p[3 * HH] * WSCALE); \
    f[4] = (_Float16)(p[4 * HH] * WSCALE); f[5] = (_Float16)(p[5 * HH] * WSCALE); \
    f[6] = (_Float16)(p[6 * HH] * WSCALE); f[7] = (_Float16)(p[7 * HH] * WSCALE); \
    dst = f;                                                                   \
    asm volatile("" : "+a"(dst));                                              \
  }
#define FINIT(i) MK(a1A_##i, gW1, i, jA) MK(a1B_##i, gW1, i, jB)               \
                 MK(a2A_##i, gW2, i, jA) MK(a2B_##i, gW2, i, jB)
  REP8(FINIT)
#undef FINIT
#undef MK

  const char* hp0 = (const char*)h0l + g * 16;  // A-fill base (k-group window)
  const char* hp1 = (const char*)h1l + g * 16;

  __syncthreads();  // staging + sWP zero visible

  for (int t = 0; t < TT; ++t) {
    const float p_in = sP[t];
    const float tm = sTm[t];
    const float ld = sLd[t];

    // ---- layer 0 (VALU, per-lane j; groups 1-3 redundant) ----
    float h0A = xtanh(b0A + s0 * w0A0 + s1 * w0A1 + p_in * w0A2 + tm * w0A3);
    float h0B = xtanh(b0B + s0 * w0B0 + s1 * w0B1 + p_in * w0B2 + tm * w0B3);
    if (lane < 16) {
      h0l[jA] = (_Float16)h0A;
      h0l[jB] = (_Float16)h0B;
    }
    __syncthreads();  // A

    // ---- layer 1: 16 MFMA, A = h0 replicated across rows, B = AGPR weights.
    // Hazard nops are DATA-CHAINED through the accumulators so the compiler
    // cannot schedule the MFMAs or the dependent VALU reads across them.
    f32x4 dA = {0.f, 0.f, 0.f, 0.f}, dB = {0.f, 0.f, 0.f, 0.f};
    asm volatile("s_nop 1" : "+v"(dA), "+v"(dB));  // VALU-init -> MFMA srcC
#define MM1(i)                                                                 \
  {                                                                            \
    f16x8 av = *(const f16x8*)(hp0 + (i) * 64);                                \
    asm("v_mfma_f32_16x16x32_f16 %0, %1, %2, %0"                               \
        : "+v"(dA) : "v"(av), "a"(a1A_##i));                                   \
    asm("v_mfma_f32_16x16x32_f16 %0, %1, %2, %0"                               \
        : "+v"(dB) : "v"(av), "a"(a1B_##i));                                   \
  }
    REP8(MM1)
#undef MM1
    asm volatile("s_nop 7\n\ts_nop 7" : "+v"(dA), "+v"(dB));  // MFMA -> VALU
    float h1A = xtanh(dA[0] * WDESCALE + b1A);
    float h1B = xtanh(dB[0] * WDESCALE + b1B);
    if (lane < 16) {
      h1l[jA] = (_Float16)h1A;
      h1l[jB] = (_Float16)h1B;
    }
    __syncthreads();  // B

    // ---- layer 2 ----
    f32x4 eA = {0.f, 0.f, 0.f, 0.f}, eB = {0.f, 0.f, 0.f, 0.f};
    asm volatile("s_nop 1" : "+v"(eA), "+v"(eB));
#define MM2(i)                                                                 \
  {                                                                            \
    f16x8 av = *(const f16x8*)(hp1 + (i) * 64);                                \
    asm("v_mfma_f32_16x16x32_f16 %0, %1, %2, %0"                               \
        : "+v"(eA) : "v"(av), "a"(a2A_##i));                                   \
    asm("v_mfma_f32_16x16x32_f16 %0, %1, %2, %0"                               \
        : "+v"(eB) : "v"(av), "a"(a2B_##i));                                   \
  }
    REP8(MM2)
#undef MM2
    asm volatile("s_nop 7\n\ts_nop 7" : "+v"(eA), "+v"(eB));
    float h2A = xtanh(eA[0] * WDESCALE + b2A);
    float h2B = xtanh(eB[0] * WDESCALE + b2B);

    // ---- output layer: per-lane partials, DPP row all-reduce (no DS) ----
    float p0 = h2A * woA0 + h2B * woB0;
    float p1 = h2A * woA1 + h2B * woB1;
    float p2 = h2A * woA2 + h2B * woB2;
    float p3 = h2A * woA3 + h2B * woB3;
    float p4 = h2A * woA4 + h2B * woB4;
    DPPADD(p0, 0x121) DPPADD(p0, 0x122) DPPADD(p0, 0x124) DPPADD(p0, 0x128)
    DPPADD(p1, 0x121) DPPADD(p1, 0x122) DPPADD(p1, 0x124) DPPADD(p1, 0x128)
    DPPADD(p2, 0x121) DPPADD(p2, 0x122) DPPADD(p2, 0x124) DPPADD(p2, 0x128)
    DPPADD(p3, 0x121) DPPADD(p3, 0x122) DPPADD(p3, 0x124) DPPADD(p3, 0x128)
    DPPADD(p4, 0x121) DPPADD(p4, 0x122) DPPADD(p4, 0x124) DPPADD(p4, 0x128)
    if (lane == 0) {  // lane 0 holds the wave's 32-j sums after row reduce
      sWP[w * 8 + 0] = p0; sWP[w * 8 + 1] = p1; sWP[w * 8 + 2] = p2;
      sWP[w * 8 + 3] = p3; sWP[w * 8 + 4] = p4;
    }
    __syncthreads();  // C

    // ---- finalize on ALL threads: cross-wave sum + transforms + state ----
    float v = sWP[lane];  // lane l: m = l&7, wave = l>>3 (m>4 slots are 0)
    DPPADD(v, 0x128)      // + rotated-by-8 within row: wave pairs
    v += __builtin_bit_cast(
        float, __builtin_amdgcn_ds_swizzle(__builtin_bit_cast(int, v), 0x401F));  // ^16
    float o0 = __builtin_bit_cast(float, __builtin_amdgcn_readlane(__builtin_bit_cast(int, v), 0)) +
               __builtin_bit_cast(float, __builtin_amdgcn_readlane(__builtin_bit_cast(int, v), 32)) + bo0;
    float o1 = __builtin_bit_cast(float, __builtin_amdgcn_readlane(__builtin_bit_cast(int, v), 1)) +
               __builtin_bit_cast(float, __builtin_amdgcn_readlane(__builtin_bit_cast(int, v), 33)) + bo1;
    float o2 = __builtin_bit_cast(float, __builtin_amdgcn_readlane(__builtin_bit_cast(int, v), 2)) +
               __builtin_bit_cast(float, __builtin_amdgcn_readlane(__builtin_bit_cast(int, v), 34)) + bo2;
    float o3 = __builtin_bit_cast(float, __builtin_amdgcn_readlane(__builtin_bit_cast(int, v), 3)) +
               __builtin_bit_cast(float, __builtin_amdgcn_readlane(__builtin_bit_cast(int, v), 35)) + bo3;
    float o4 = __builtin_bit_cast(float, __builtin_amdgcn_readlane(__builtin_bit_cast(int, v), 4)) +
               __builtin_bit_cast(float, __builtin_amdgcn_readlane(__builtin_bit_cast(int, v), 36)) + bo4;
    if (tid == 0) {
      gout[t] = o4;           // q_output[t] = raw mlp output m=4 at state_t
      gout[TT + t] = s0;      // s_snow_nn[t] (pre-update)
      gout[2 * TT + t] = s1;  // s_water_nn[t]
    }
    float sh0 = xsinh(o0), sh1 = xsinh(o1), sh2 = xsinh(o2);
    float e3 = xexp(o3), e4 = xexp(o4);
    float stn = xstep(-tm), st0 = xstep(s0), st1 = xstep(s1);
    float psn = fmaxf(sh0 * stn, 0.0f);
    float prn = fmaxf(sh1, 0.0f);
    float mm = fmaxf(st0 * sh2, 0.0f);
    float evt = st1 * e3 * ld;
    float qq = st1 * e4;
    s0 += psn - mm;                 // DT = 1
    s1 += prn + mm - evt - qq;
  }
}

extern "C" void kernel_launch(void* const* d_in, const int* in_sizes, int n_in,
                              void* d_out, int out_size, void* d_ws, size_t ws_size,
                              hipStream_t stream) {
  const float* gin   = (const float*)d_in[0];
  const float* gdayl = (const float*)d_in[1];
  const float* gW0   = (const float*)d_in[2];
  const float* gb0   = (const float*)d_in[3];
  const float* gW1   = (const float*)d_in[4];
  const float* gb1   = (const float*)d_in[5];
  const float* gW2   = (const float*)d_in[6];
  const float* gb2   = (const float*)d_in[7];
  const float* gWout = (const float*)d_in[8];
  const float* gbout = (const float*)d_in[9];
  float* gout = (float*)d_out;
  exphydro_scan<<<dim3(1), dim3(512), 0, stream>>>(
      gin, gdayl, gW0, gb0, gW1, gb1, gW2, gb2, gWout, gbout, gout);
}